// Round 7
// baseline (65.543 us; speedup 1.0000x reference)
//
#include <hip/hip_runtime.h>

#define NN 1024
#define BB 64
#define CHUNKS 32
#define KS 8   // k-splits per batch in the DFT kernel

// ---------------------------------------------------------------------------
// Kernel 1: register-accumulated partial diagonal sums, v3.
// CHUNKS=32: 2048 blocks -> 8 blocks/CU (32 waves/CU) given VGPR<=64
// (forced via __launch_bounds__(256,8)).
// Uniform trip count: nvec/nit are wave-uniform, so rows only execute the
// load+add groups they need (avg 2.2 of 4) — ~45% fewer dynamic instructions.
__global__ __launch_bounds__(256, 8) void diag_partial(const float* __restrict__ attns,
                                                       float* __restrict__ partial) {
    __shared__ float lds[4][1032];  // per-wave dump region (+8 pad for d+r reads)
    const int c = blockIdx.x;       // 0..31
    const int b = blockIdx.y;
    const int tid = threadIdx.x;
    const int wid = tid >> 6, lane = tid & 63;
    const int r = c & 3;

    float4 acc0 = make_float4(0.f, 0.f, 0.f, 0.f);
    float4 acc1 = acc0, acc2 = acc0, acc3 = acc0;

    const float* base = attns + (size_t)b * NN * NN;

#pragma unroll 2
    for (int t = 0; t < 8; ++t) {
        const int i = c + 32 * wid + 128 * t;     // wave-uniform row, i ≡ c (mod 32)
        const int jbase = i - r;                  // 4-aligned, wave-uniform
        const int nvec = (NN - jbase) >> 2;       // wave-uniform, 1..256
        const int nit = (nvec + 63) >> 6;         // wave-uniform, 1..4
        const int last = nvec - 1;
        const float4* f4 = (const float4*)(base + (size_t)i * NN + jbase);

        // issue all needed loads first (uniform guards), adds after
        float4 x0, x1, x2, x3;
        x0 = f4[lane < last ? lane : last];
        if (nit > 1) x1 = f4[lane + 64 < last ? lane + 64 : last];
        if (nit > 2) x2 = f4[lane + 128 < last ? lane + 128 : last];
        if (nit > 3) x3 = f4[lane + 192 < last ? lane + 192 : last];

        // zero invalid lanes of the (single) partial group: it == nit-1
        {
            const int rem = nvec - ((nit - 1) << 6);   // 1..64
            const bool ok = lane < rem;
            float4* xe = (nit == 1) ? &x0 : (nit == 2) ? &x1 : (nit == 3) ? &x2 : &x3;
            xe->x = ok ? xe->x : 0.f;
            xe->y = ok ? xe->y : 0.f;
            xe->z = ok ? xe->z : 0.f;
            xe->w = ok ? xe->w : 0.f;
        }
        // head mask (it=0, lane=0): components with j < i  (d < 0)
        if (lane == 0) {
            if (r > 0) x0.x = 0.f;
            if (r > 1) x0.y = 0.f;
            if (r > 2) x0.z = 0.f;
        }

        acc0.x += x0.x; acc0.y += x0.y; acc0.z += x0.z; acc0.w += x0.w;
        if (nit > 1) { acc1.x += x1.x; acc1.y += x1.y; acc1.z += x1.z; acc1.w += x1.w; }
        if (nit > 2) { acc2.x += x2.x; acc2.y += x2.y; acc2.z += x2.z; acc2.w += x2.w; }
        if (nit > 3) { acc3.x += x3.x; acc3.y += x3.y; acc3.z += x3.z; acc3.w += x3.w; }
    }

    // dump: lds[wid][4*(lane+64*it)+comp] — bijective onto [0,1024)
    float4* lrow = (float4*)lds[wid];
    lrow[lane]       = acc0;
    lrow[lane + 64]  = acc1;
    lrow[lane + 128] = acc2;
    lrow[lane + 192] = acc3;
    if (tid < 32) lds[tid >> 3][1024 + (tid & 7)] = 0.f;   // zero the +pad tail
    __syncthreads();

    // partial[b][c][d] = sum over waves of lds[w][d + r]
    float* outp = partial + ((size_t)b * CHUNKS + c) * NN;
    for (int d = tid; d < NN; d += 256)
        outp[d] = (lds[0][d + r] + lds[1][d + r]) + (lds[2][d + r] + lds[3][d + r]);
}

// ---------------------------------------------------------------------------
// Kernel 2: reduce chunk partials -> parity-split means:
//   wp[b][d] = w[d] + w[d+512],  wm[b][d] = w[d] - w[d+512]   (d < 512)
__global__ __launch_bounds__(256) void reduce_waves(const float* __restrict__ partial,
                                                    float* __restrict__ wpm) {
    const int idx = blockIdx.x * blockDim.x + threadIdx.x;  // BB*512 threads
    const int b = idx >> 9;
    const int d = idx & 511;
    const float* pb = partial + (size_t)b * CHUNKS * NN;
    float slo = 0.f, shi = 0.f;
#pragma unroll 8
    for (int c = 0; c < CHUNKS; ++c) {
        slo += pb[c * NN + d];
        shi += pb[c * NN + d + 512];
    }
    const float wlo = slo / (float)(NN - d);
    const float whi = shi / (float)(512 - d);
    wpm[(size_t)b * NN + d]       = wlo + whi;   // wp
    wpm[(size_t)b * NN + 512 + d] = wlo - whi;   // wm
}

// ---------------------------------------------------------------------------
// Kernel 3: even/odd-decimated DFT, bins k = 1..512.
// X_k = sum_{d<512} (k even ? wp : wm)[d] * e^{-2pi i k d/1024}
// Grid (b, ks=8) x 512 threads; k = 1 + ks*64 + (tid>>3); d-phase dp = tid&7.
__global__ __launch_bounds__(512) void dft_part(const float* __restrict__ wpm,
                                                float* __restrict__ kparts) {
    __shared__ float wp[512], wm[512];
    __shared__ float cosT[NN], msinT[NN];
    __shared__ float redmax[8], redsum[8];
    const int ks = blockIdx.x & (KS - 1);
    const int b = blockIdx.x >> 3;
    const int tid = threadIdx.x;
    const float C = 6.283185307179586f / 1024.0f;

    {
        const float* src = wpm + (size_t)b * NN;
        wp[tid & 511] = src[tid & 511];
        wm[tid & 511] = src[512 + (tid & 511)];
        cosT[tid] = cosf((float)tid * C);
        msinT[tid] = -sinf((float)tid * C);
        const int t2 = tid + 512;
        cosT[t2] = cosf((float)t2 * C);
        msinT[t2] = -sinf((float)t2 * C);
    }
    __syncthreads();

    const int k = 1 + ks * 64 + (tid >> 3);
    const int dp = tid & 7;
    const float* wsel = (k & 1) ? wm : wp;
    const int kstep = (k << 3) & (NN - 1);

    float re = 0.f, im = 0.f;
    int t = (k * dp) & (NN - 1);
#pragma unroll 8
    for (int it = 0; it < 64; ++it) {
        const float wv = wsel[dp + 8 * it];
        re = fmaf(wv, cosT[t], re);
        im = fmaf(wv, msinT[t], im);
        t = (t + kstep) & (NN - 1);
    }
    re += __shfl_xor(re, 1, 64); re += __shfl_xor(re, 2, 64); re += __shfl_xor(re, 4, 64);
    im += __shfl_xor(im, 1, 64); im += __shfl_xor(im, 2, 64); im += __shfl_xor(im, 4, 64);
    const float spec = sqrtf(re * re + im * im);

    float mx = spec;
    float sm = (dp == 0) ? spec : 0.f;
    for (int off = 8; off < 64; off <<= 1) {
        mx = fmaxf(mx, __shfl_xor(mx, off, 64));
        sm += __shfl_xor(sm, off, 64);
    }
    const int wid = tid >> 6, lane = tid & 63;
    if (lane == 0) { redmax[wid] = mx; redsum[wid] = sm; }
    __syncthreads();
    if (tid == 0) {
        float M = redmax[0], S = redsum[0];
        for (int i = 1; i < 8; ++i) { M = fmaxf(M, redmax[i]); S += redsum[i]; }
        kparts[((size_t)b * KS + ks) * 2 + 0] = M;
        kparts[((size_t)b * KS + ks) * 2 + 1] = S;
    }
}

// ---------------------------------------------------------------------------
// Kernel 4: judgement per batch, mean over batches.
__global__ __launch_bounds__(64) void finalize(const float* __restrict__ kparts,
                                               float* __restrict__ out) {
    const int lane = threadIdx.x;   // one lane per batch
    float M = 0.f, S = 0.f;
#pragma unroll
    for (int s = 0; s < KS; ++s) {
        M = fmaxf(M, kparts[((size_t)lane * KS + s) * 2 + 0]);
        S += kparts[((size_t)lane * KS + s) * 2 + 1];
    }
    float j = 1.0f - M / S;
    for (int off = 32; off; off >>= 1) j += __shfl_xor(j, off, 64);
    if (lane == 0) out[0] = j * (1.0f / 64.0f);
}

// ---------------------------------------------------------------------------
extern "C" void kernel_launch(void* const* d_in, const int* in_sizes, int n_in,
                              void* d_out, int out_size, void* d_ws, size_t ws_size,
                              hipStream_t stream) {
    const float* attns = (const float*)d_in[0];
    float* out = (float*)d_out;

    // workspace: [partial: B*CHUNKS*N = 8MB] [wpm: B*N] [kparts: B*KS*2]
    float* partial = (float*)d_ws;
    float* wpm     = partial + (size_t)BB * CHUNKS * NN;
    float* kparts  = wpm + (size_t)BB * NN;

    diag_partial<<<dim3(CHUNKS, BB), 256, 0, stream>>>(attns, partial);
    reduce_waves<<<(BB * 512) / 256, 256, 0, stream>>>(partial, wpm);
    dft_part<<<BB * KS, 512, 0, stream>>>(wpm, kparts);
    finalize<<<1, 64, 0, stream>>>(kparts, out);
}

// Round 8
// 43.982 us; speedup vs baseline: 1.4902x; 1.4902x over previous
//
#include <hip/hip_runtime.h>

#define NN 1024
#define BB 64
#define CHUNKS 32
#define KS 8   // k-splits per batch in the DFT kernel

// ---------------------------------------------------------------------------
// Kernel 1: balanced diagonal partial sums, v4.
// Block t pairs 16 LONG rows [16t,16t+16) with 16 SHORT rows
// [1008-16t, 1008-16t+16)  ->  ~64 KB per block, constant (load balance).
// Wave w takes rows ≡ w (mod 4) of both groups => r = i&3 = w per wave.
// With jbase = i - w, lane v = lane+64*it reads float4 at col jbase+4v,
// contributing to d = 4v + comp - w: FIXED (lane,it,comp)->d register map.
// Long rows: nvec in [129,256] -> groups 0,1 unmasked, 4 groups loaded.
// Short rows: nvec in [1,128]  -> exactly 2 groups loaded.
// All loads unconditional straight-line (clamped index + cndmask zero).
__global__ __launch_bounds__(256) void diag_partial(const float* __restrict__ attns,
                                                    float* __restrict__ partial) {
    __shared__ float lds[4][1032];  // per-wave dump (+8 pad for d+w reads)
    const int t = blockIdx.x;       // 0..31
    const int b = blockIdx.y;
    const int tid = threadIdx.x;
    const int w = tid >> 6, lane = tid & 63;   // w == r for this wave

    float4 acc0 = make_float4(0.f, 0.f, 0.f, 0.f);
    float4 acc1 = acc0, acc2 = acc0, acc3 = acc0;

    const float* base = attns + (size_t)b * NN * NN;

#pragma unroll
    for (int k = 0; k < 4; ++k) {
        // ---- long row: i = 16t + w + 4k ----
        const int jbT = 16 * t + 4 * k;
        const int nvT = 256 - 4 * t - k;            // wave-uniform, 129..256
        const float4* fT = (const float4*)(base + (size_t)(jbT + w) * NN + jbT);
        const int lastT = nvT - 1;
        // ---- short row: i = 1008 - 16t + w + 4k ----
        const int jbB = 1008 - 16 * t + 4 * k;
        const int nvB = 4 + 4 * t - k;              // wave-uniform, 1..128
        const float4* fB = (const float4*)(base + (size_t)(jbB + w) * NN + jbB);
        const int lastB = nvB - 1;

        // issue all 6 loads up front (unconditional)
        float4 x0 = fT[lane];
        float4 x1 = fT[lane + 64];
        float4 x2 = fT[lane + 128 < lastT ? lane + 128 : lastT];
        float4 x3 = fT[lane + 192 < lastT ? lane + 192 : lastT];
        float4 y0 = fB[lane < lastB ? lane : lastB];
        float4 y1 = fB[lane + 64 < lastB ? lane + 64 : lastB];

        // masks: long groups 2,3; short groups 0,1
        {
            const bool ok2 = lane + 128 < nvT;
            const bool ok3 = lane + 192 < nvT;
            x2.x = ok2 ? x2.x : 0.f; x2.y = ok2 ? x2.y : 0.f;
            x2.z = ok2 ? x2.z : 0.f; x2.w = ok2 ? x2.w : 0.f;
            x3.x = ok3 ? x3.x : 0.f; x3.y = ok3 ? x3.y : 0.f;
            x3.z = ok3 ? x3.z : 0.f; x3.w = ok3 ? x3.w : 0.f;
            const bool p0 = lane < nvB;
            const bool p1 = lane + 64 < nvB;
            y0.x = p0 ? y0.x : 0.f; y0.y = p0 ? y0.y : 0.f;
            y0.z = p0 ? y0.z : 0.f; y0.w = p0 ? y0.w : 0.f;
            y1.x = p1 ? y1.x : 0.f; y1.y = p1 ? y1.y : 0.f;
            y1.z = p1 ? y1.z : 0.f; y1.w = p1 ? y1.w : 0.f;
        }
        // head mask (group 0, lane 0): components with comp < w  (j < i)
        if (lane == 0) {
            if (w > 0) { x0.x = 0.f; y0.x = 0.f; }
            if (w > 1) { x0.y = 0.f; y0.y = 0.f; }
            if (w > 2) { x0.z = 0.f; y0.z = 0.f; }
        }

        acc0.x += x0.x + y0.x; acc0.y += x0.y + y0.y;
        acc0.z += x0.z + y0.z; acc0.w += x0.w + y0.w;
        acc1.x += x1.x + y1.x; acc1.y += x1.y + y1.y;
        acc1.z += x1.z + y1.z; acc1.w += x1.w + y1.w;
        acc2.x += x2.x; acc2.y += x2.y; acc2.z += x2.z; acc2.w += x2.w;
        acc3.x += x3.x; acc3.y += x3.y; acc3.z += x3.z; acc3.w += x3.w;
    }

    // dump: lds[w][4*(lane+64*it)+comp] — bijective onto [0,1024) per wave
    float4* lrow = (float4*)lds[w];
    lrow[lane]       = acc0;
    lrow[lane + 64]  = acc1;
    lrow[lane + 128] = acc2;
    lrow[lane + 192] = acc3;
    if (tid < 32) lds[tid >> 3][1024 + (tid & 7)] = 0.f;   // zero pad tail
    __syncthreads();

    // partial[b][t][d] = sum over waves of lds[wv][d + wv]
    float* outp = partial + ((size_t)b * CHUNKS + t) * NN;
    for (int d = tid; d < NN; d += 256)
        outp[d] = (lds[0][d] + lds[1][d + 1]) + (lds[2][d + 2] + lds[3][d + 3]);
}

// ---------------------------------------------------------------------------
// Kernel 2: reduce chunk partials -> parity-split means:
//   wp[b][d] = w[d] + w[d+512],  wm[b][d] = w[d] - w[d+512]   (d < 512)
__global__ __launch_bounds__(256) void reduce_waves(const float* __restrict__ partial,
                                                    float* __restrict__ wpm) {
    const int idx = blockIdx.x * blockDim.x + threadIdx.x;  // BB*512 threads
    const int b = idx >> 9;
    const int d = idx & 511;
    const float* pb = partial + (size_t)b * CHUNKS * NN;
    float slo = 0.f, shi = 0.f;
#pragma unroll 8
    for (int c = 0; c < CHUNKS; ++c) {
        slo += pb[c * NN + d];
        shi += pb[c * NN + d + 512];
    }
    const float wlo = slo / (float)(NN - d);
    const float whi = shi / (float)(512 - d);
    wpm[(size_t)b * NN + d]       = wlo + whi;   // wp
    wpm[(size_t)b * NN + 512 + d] = wlo - whi;   // wm
}

// ---------------------------------------------------------------------------
// Kernel 3: even/odd-decimated DFT, bins k = 1..512.
// X_k = sum_{d<512} (k even ? wp : wm)[d] * e^{-2pi i k d/1024}
// Grid (b, ks=8) x 512 threads; k = 1 + ks*64 + (tid>>3); d-phase dp = tid&7.
__global__ __launch_bounds__(512) void dft_part(const float* __restrict__ wpm,
                                                float* __restrict__ kparts) {
    __shared__ float wp[512], wm[512];
    __shared__ float cosT[NN], msinT[NN];
    __shared__ float redmax[8], redsum[8];
    const int ks = blockIdx.x & (KS - 1);
    const int b = blockIdx.x >> 3;
    const int tid = threadIdx.x;
    const float C = 6.283185307179586f / 1024.0f;

    {
        const float* src = wpm + (size_t)b * NN;
        wp[tid & 511] = src[tid & 511];
        wm[tid & 511] = src[512 + (tid & 511)];
        cosT[tid] = cosf((float)tid * C);
        msinT[tid] = -sinf((float)tid * C);
        const int t2 = tid + 512;
        cosT[t2] = cosf((float)t2 * C);
        msinT[t2] = -sinf((float)t2 * C);
    }
    __syncthreads();

    const int k = 1 + ks * 64 + (tid >> 3);
    const int dp = tid & 7;
    const float* wsel = (k & 1) ? wm : wp;
    const int kstep = (k << 3) & (NN - 1);

    float re = 0.f, im = 0.f;
    int t = (k * dp) & (NN - 1);
#pragma unroll 8
    for (int it = 0; it < 64; ++it) {
        const float wv = wsel[dp + 8 * it];
        re = fmaf(wv, cosT[t], re);
        im = fmaf(wv, msinT[t], im);
        t = (t + kstep) & (NN - 1);
    }
    re += __shfl_xor(re, 1, 64); re += __shfl_xor(re, 2, 64); re += __shfl_xor(re, 4, 64);
    im += __shfl_xor(im, 1, 64); im += __shfl_xor(im, 2, 64); im += __shfl_xor(im, 4, 64);
    const float spec = sqrtf(re * re + im * im);

    float mx = spec;
    float sm = (dp == 0) ? spec : 0.f;
    for (int off = 8; off < 64; off <<= 1) {
        mx = fmaxf(mx, __shfl_xor(mx, off, 64));
        sm += __shfl_xor(sm, off, 64);
    }
    const int wid = tid >> 6, lane = tid & 63;
    if (lane == 0) { redmax[wid] = mx; redsum[wid] = sm; }
    __syncthreads();
    if (tid == 0) {
        float M = redmax[0], S = redsum[0];
        for (int i = 1; i < 8; ++i) { M = fmaxf(M, redmax[i]); S += redsum[i]; }
        kparts[((size_t)b * KS + ks) * 2 + 0] = M;
        kparts[((size_t)b * KS + ks) * 2 + 1] = S;
    }
}

// ---------------------------------------------------------------------------
// Kernel 4: judgement per batch, mean over batches.
__global__ __launch_bounds__(64) void finalize(const float* __restrict__ kparts,
                                               float* __restrict__ out) {
    const int lane = threadIdx.x;   // one lane per batch
    float M = 0.f, S = 0.f;
#pragma unroll
    for (int s = 0; s < KS; ++s) {
        M = fmaxf(M, kparts[((size_t)lane * KS + s) * 2 + 0]);
        S += kparts[((size_t)lane * KS + s) * 2 + 1];
    }
    float j = 1.0f - M / S;
    for (int off = 32; off; off >>= 1) j += __shfl_xor(j, off, 64);
    if (lane == 0) out[0] = j * (1.0f / 64.0f);
}

// ---------------------------------------------------------------------------
extern "C" void kernel_launch(void* const* d_in, const int* in_sizes, int n_in,
                              void* d_out, int out_size, void* d_ws, size_t ws_size,
                              hipStream_t stream) {
    const float* attns = (const float*)d_in[0];
    float* out = (float*)d_out;

    // workspace: [partial: B*CHUNKS*N = 8MB] [wpm: B*N] [kparts: B*KS*2]
    float* partial = (float*)d_ws;
    float* wpm     = partial + (size_t)BB * CHUNKS * NN;
    float* kparts  = wpm + (size_t)BB * NN;

    diag_partial<<<dim3(CHUNKS, BB), 256, 0, stream>>>(attns, partial);
    reduce_waves<<<(BB * 512) / 256, 256, 0, stream>>>(partial, wpm);
    dft_part<<<BB * KS, 512, 0, stream>>>(wpm, kparts);
    finalize<<<1, 64, 0, stream>>>(kparts, out);
}

// Round 9
// 40.024 us; speedup vs baseline: 1.6376x; 1.0989x over previous
//
#include <hip/hip_runtime.h>

#define NN 1024
#define BB 64
#define CHUNKS 32
#define KS 8   // k-splits per batch in the DFT kernel

// ---------------------------------------------------------------------------
// Kernel 1: balanced diagonal partial sums, v5 (2-deep software pipeline).
// Block t pairs 16 LONG rows [16t,16t+16) with 16 SHORT rows
// [1008-16t,1008-16t+16). Wave w takes rows ≡ w (mod 4): r = w constant.
// Fixed (lane,group,comp)->d register mapping, d = 4*(lane+64*g) + comp - w.
// Pipeline: issue loads for pair g+1 before consuming pair g.
__global__ __launch_bounds__(256) void diag_partial(const float* __restrict__ attns,
                                                    float* __restrict__ partial) {
    __shared__ float lds[4][1032];
    const int t = blockIdx.x;       // 0..31
    const int b = blockIdx.y;
    const int tid = threadIdx.x;
    const int w = tid >> 6, lane = tid & 63;

    float4 acc0 = make_float4(0.f, 0.f, 0.f, 0.f);
    float4 acc1 = acc0, acc2 = acc0, acc3 = acc0;

    const float* base = attns + (size_t)b * NN * NN;

    // per-k row-pair parameters (wave-uniform)
#define ROWPAIR(k, fT, fB, nvT, nvB)                                          \
    const int jbT##k = 16 * t + 4 * (k);                                      \
    const int nvT = 256 - 4 * t - (k);                                        \
    const float4* fT = (const float4*)(base + (size_t)(jbT##k + w) * NN + jbT##k); \
    const int jbB##k = 1008 - 16 * t + 4 * (k);                               \
    const int nvB = 4 + 4 * t - (k);                                          \
    const float4* fB = (const float4*)(base + (size_t)(jbB##k + w) * NN + jbB##k);

    ROWPAIR(0, fT0, fB0, nvT0, nvB0)
    ROWPAIR(1, fT1, fB1, nvT1, nvB1)
    ROWPAIR(2, fT2, fB2, nvT2, nvB2)
    ROWPAIR(3, fT3, fB3, nvT3, nvB3)
#undef ROWPAIR

    // LOAD(g): 6 unconditional loads for pair g into named regs
#define LOADP(g, fT, fB, nvT, nvB)                                            \
    float4 xa##g = fT[lane];                                                  \
    float4 xb##g = fT[lane + 64];                                             \
    float4 xc##g = fT[lane + 128 < nvT - 1 ? lane + 128 : nvT - 1];           \
    float4 xd##g = fT[lane + 192 < nvT - 1 ? lane + 192 : nvT - 1];           \
    float4 ya##g = fB[lane < nvB - 1 ? lane : nvB - 1];                       \
    float4 yb##g = fB[lane + 64 < nvB - 1 ? lane + 64 : nvB - 1];

    // CONS(g): mask + accumulate pair g
#define CONSP(g, nvT, nvB)                                                    \
    {                                                                         \
        const bool ok2 = lane + 128 < nvT, ok3 = lane + 192 < nvT;            \
        const bool p0 = lane < nvB, p1 = lane + 64 < nvB;                     \
        xc##g.x = ok2 ? xc##g.x : 0.f; xc##g.y = ok2 ? xc##g.y : 0.f;         \
        xc##g.z = ok2 ? xc##g.z : 0.f; xc##g.w = ok2 ? xc##g.w : 0.f;         \
        xd##g.x = ok3 ? xd##g.x : 0.f; xd##g.y = ok3 ? xd##g.y : 0.f;         \
        xd##g.z = ok3 ? xd##g.z : 0.f; xd##g.w = ok3 ? xd##g.w : 0.f;         \
        ya##g.x = p0 ? ya##g.x : 0.f; ya##g.y = p0 ? ya##g.y : 0.f;           \
        ya##g.z = p0 ? ya##g.z : 0.f; ya##g.w = p0 ? ya##g.w : 0.f;           \
        yb##g.x = p1 ? yb##g.x : 0.f; yb##g.y = p1 ? yb##g.y : 0.f;           \
        yb##g.z = p1 ? yb##g.z : 0.f; yb##g.w = p1 ? yb##g.w : 0.f;           \
        if (lane == 0) {                                                      \
            if (w > 0) { xa##g.x = 0.f; ya##g.x = 0.f; }                      \
            if (w > 1) { xa##g.y = 0.f; ya##g.y = 0.f; }                      \
            if (w > 2) { xa##g.z = 0.f; ya##g.z = 0.f; }                      \
        }                                                                     \
        acc0.x += xa##g.x + ya##g.x; acc0.y += xa##g.y + ya##g.y;             \
        acc0.z += xa##g.z + ya##g.z; acc0.w += xa##g.w + ya##g.w;             \
        acc1.x += xb##g.x + yb##g.x; acc1.y += xb##g.y + yb##g.y;             \
        acc1.z += xb##g.z + yb##g.z; acc1.w += xb##g.w + yb##g.w;             \
        acc2.x += xc##g.x; acc2.y += xc##g.y;                                 \
        acc2.z += xc##g.z; acc2.w += xc##g.w;                                 \
        acc3.x += xd##g.x; acc3.y += xd##g.y;                                 \
        acc3.z += xd##g.z; acc3.w += xd##g.w;                                 \
    }

    LOADP(0, fT0, fB0, nvT0, nvB0)
    LOADP(1, fT1, fB1, nvT1, nvB1)
    CONSP(0, nvT0, nvB0)
    LOADP(2, fT2, fB2, nvT2, nvB2)
    CONSP(1, nvT1, nvB1)
    LOADP(3, fT3, fB3, nvT3, nvB3)
    CONSP(2, nvT2, nvB2)
    CONSP(3, nvT3, nvB3)
#undef LOADP
#undef CONSP

    // dump: lds[w][4*(lane+64*g)+comp] — bijective onto [0,1024) per wave
    float4* lrow = (float4*)lds[w];
    lrow[lane]       = acc0;
    lrow[lane + 64]  = acc1;
    lrow[lane + 128] = acc2;
    lrow[lane + 192] = acc3;
    if (tid < 32) lds[tid >> 3][1024 + (tid & 7)] = 0.f;
    __syncthreads();

    float* outp = partial + ((size_t)b * CHUNKS + t) * NN;
    for (int d = tid; d < NN; d += 256)
        outp[d] = (lds[0][d] + lds[1][d + 1]) + (lds[2][d + 2] + lds[3][d + 3]);
}

// ---------------------------------------------------------------------------
// Kernel 2: reduce chunk partials -> parity-split means.
__global__ __launch_bounds__(256) void reduce_waves(const float* __restrict__ partial,
                                                    float* __restrict__ wpm) {
    const int idx = blockIdx.x * blockDim.x + threadIdx.x;  // BB*512 threads
    const int b = idx >> 9;
    const int d = idx & 511;
    const float* pb = partial + (size_t)b * CHUNKS * NN;
    float slo = 0.f, shi = 0.f;
#pragma unroll 8
    for (int c = 0; c < CHUNKS; ++c) {
        slo += pb[c * NN + d];
        shi += pb[c * NN + d + 512];
    }
    const float wlo = slo / (float)(NN - d);
    const float whi = shi / (float)(512 - d);
    wpm[(size_t)b * NN + d]       = wlo + whi;   // wp
    wpm[(size_t)b * NN + 512 + d] = wlo - whi;   // wm
}

// ---------------------------------------------------------------------------
// Kernel 3: even/odd-decimated DFT, float2 twiddles, fast-trig table build.
__global__ __launch_bounds__(512) void dft_part(const float* __restrict__ wpm,
                                                float* __restrict__ kparts) {
    __shared__ float wp[512], wm[512];
    __shared__ float2 tw[NN];       // (cos, -sin)
    __shared__ float redmax[8], redsum[8];
    const int ks = blockIdx.x & (KS - 1);
    const int b = blockIdx.x >> 3;
    const int tid = threadIdx.x;
    const float C = 6.283185307179586f / 1024.0f;

    {
        const float* src = wpm + (size_t)b * NN;
        wp[tid & 511] = src[tid & 511];
        wm[tid & 511] = src[512 + (tid & 511)];
        float s0, c0, s1, c1;
        __sincosf((float)tid * C, &s0, &c0);
        __sincosf((float)(tid + 512) * C, &s1, &c1);
        tw[tid]       = make_float2(c0, -s0);
        tw[tid + 512] = make_float2(c1, -s1);
    }
    __syncthreads();

    const int k = 1 + ks * 64 + (tid >> 3);
    const int dp = tid & 7;
    const float* wsel = (k & 1) ? wm : wp;
    const int kstep = (k << 3) & (NN - 1);

    float re = 0.f, im = 0.f;
    int t = (k * dp) & (NN - 1);
#pragma unroll 8
    for (int it = 0; it < 64; ++it) {
        const float2 c = tw[t];
        const float wv = wsel[dp + 8 * it];
        re = fmaf(wv, c.x, re);
        im = fmaf(wv, c.y, im);
        t = (t + kstep) & (NN - 1);
    }
    re += __shfl_xor(re, 1, 64); re += __shfl_xor(re, 2, 64); re += __shfl_xor(re, 4, 64);
    im += __shfl_xor(im, 1, 64); im += __shfl_xor(im, 2, 64); im += __shfl_xor(im, 4, 64);
    const float spec = sqrtf(re * re + im * im);

    float mx = spec;
    float sm = (dp == 0) ? spec : 0.f;
    for (int off = 8; off < 64; off <<= 1) {
        mx = fmaxf(mx, __shfl_xor(mx, off, 64));
        sm += __shfl_xor(sm, off, 64);
    }
    const int wid = tid >> 6, lane = tid & 63;
    if (lane == 0) { redmax[wid] = mx; redsum[wid] = sm; }
    __syncthreads();
    if (tid == 0) {
        float M = redmax[0], S = redsum[0];
        for (int i = 1; i < 8; ++i) { M = fmaxf(M, redmax[i]); S += redsum[i]; }
        kparts[((size_t)b * KS + ks) * 2 + 0] = M;
        kparts[((size_t)b * KS + ks) * 2 + 1] = S;
    }
}

// ---------------------------------------------------------------------------
// Kernel 4: judgement per batch, mean over batches.
__global__ __launch_bounds__(64) void finalize(const float* __restrict__ kparts,
                                               float* __restrict__ out) {
    const int lane = threadIdx.x;
    float M = 0.f, S = 0.f;
#pragma unroll
    for (int s = 0; s < KS; ++s) {
        M = fmaxf(M, kparts[((size_t)lane * KS + s) * 2 + 0]);
        S += kparts[((size_t)lane * KS + s) * 2 + 1];
    }
    float j = 1.0f - M / S;
    for (int off = 32; off; off >>= 1) j += __shfl_xor(j, off, 64);
    if (lane == 0) out[0] = j * (1.0f / 64.0f);
}

// ---------------------------------------------------------------------------
extern "C" void kernel_launch(void* const* d_in, const int* in_sizes, int n_in,
                              void* d_out, int out_size, void* d_ws, size_t ws_size,
                              hipStream_t stream) {
    const float* attns = (const float*)d_in[0];
    float* out = (float*)d_out;

    float* partial = (float*)d_ws;
    float* wpm     = partial + (size_t)BB * CHUNKS * NN;
    float* kparts  = wpm + (size_t)BB * NN;

    diag_partial<<<dim3(CHUNKS, BB), 256, 0, stream>>>(attns, partial);
    reduce_waves<<<(BB * 512) / 256, 256, 0, stream>>>(partial, wpm);
    dft_part<<<BB * KS, 512, 0, stream>>>(wpm, kparts);
    finalize<<<1, 64, 0, stream>>>(kparts, out);
}

// Round 10
// 39.988 us; speedup vs baseline: 1.6391x; 1.0009x over previous
//
#include <hip/hip_runtime.h>

#define NN 1024
#define BB 64
#define CHUNKS 32
#define KS 8   // k-splits per batch in the DFT kernel

// ---------------------------------------------------------------------------
// Kernel 1: balanced diagonal partial sums, v6 (3-deep software pipeline).
// Block t pairs 16 LONG rows [16t,16t+16) with 16 SHORT rows
// [1008-16t,1008-16t+16). Wave w takes rows ≡ w (mod 4): r = w constant.
// Fixed (lane,group,comp)->d register map: d = 4*(lane+64*g) + comp - w.
// Pipeline: L0 L1 L2 C0 L3 C1 C2 C3 — first consume has 12 loads in flight.
__global__ __launch_bounds__(256) void diag_partial(const float* __restrict__ attns,
                                                    float* __restrict__ partial) {
    __shared__ float lds[4][1032];
    const int t = blockIdx.x;       // 0..31
    const int b = blockIdx.y;
    const int tid = threadIdx.x;
    const int w = tid >> 6, lane = tid & 63;

    float4 acc0 = make_float4(0.f, 0.f, 0.f, 0.f);
    float4 acc1 = acc0, acc2 = acc0, acc3 = acc0;

    const float* base = attns + (size_t)b * NN * NN;

#define ROWPAIR(k, fT, fB, nvT, nvB)                                          \
    const int jbT##k = 16 * t + 4 * (k);                                      \
    const int nvT = 256 - 4 * t - (k);                                        \
    const float4* fT = (const float4*)(base + (size_t)(jbT##k + w) * NN + jbT##k); \
    const int jbB##k = 1008 - 16 * t + 4 * (k);                               \
    const int nvB = 4 + 4 * t - (k);                                          \
    const float4* fB = (const float4*)(base + (size_t)(jbB##k + w) * NN + jbB##k);

    ROWPAIR(0, fT0, fB0, nvT0, nvB0)
    ROWPAIR(1, fT1, fB1, nvT1, nvB1)
    ROWPAIR(2, fT2, fB2, nvT2, nvB2)
    ROWPAIR(3, fT3, fB3, nvT3, nvB3)
#undef ROWPAIR

#define LOADP(g, fT, fB, nvT, nvB)                                            \
    float4 xa##g = fT[lane];                                                  \
    float4 xb##g = fT[lane + 64];                                             \
    float4 xc##g = fT[lane + 128 < nvT - 1 ? lane + 128 : nvT - 1];           \
    float4 xd##g = fT[lane + 192 < nvT - 1 ? lane + 192 : nvT - 1];           \
    float4 ya##g = fB[lane < nvB - 1 ? lane : nvB - 1];                       \
    float4 yb##g = fB[lane + 64 < nvB - 1 ? lane + 64 : nvB - 1];

#define CONSP(g, nvT, nvB)                                                    \
    {                                                                         \
        const bool ok2 = lane + 128 < nvT, ok3 = lane + 192 < nvT;            \
        const bool p0 = lane < nvB, p1 = lane + 64 < nvB;                     \
        xc##g.x = ok2 ? xc##g.x : 0.f; xc##g.y = ok2 ? xc##g.y : 0.f;         \
        xc##g.z = ok2 ? xc##g.z : 0.f; xc##g.w = ok2 ? xc##g.w : 0.f;         \
        xd##g.x = ok3 ? xd##g.x : 0.f; xd##g.y = ok3 ? xd##g.y : 0.f;         \
        xd##g.z = ok3 ? xd##g.z : 0.f; xd##g.w = ok3 ? xd##g.w : 0.f;         \
        ya##g.x = p0 ? ya##g.x : 0.f; ya##g.y = p0 ? ya##g.y : 0.f;           \
        ya##g.z = p0 ? ya##g.z : 0.f; ya##g.w = p0 ? ya##g.w : 0.f;           \
        yb##g.x = p1 ? yb##g.x : 0.f; yb##g.y = p1 ? yb##g.y : 0.f;           \
        yb##g.z = p1 ? yb##g.z : 0.f; yb##g.w = p1 ? yb##g.w : 0.f;           \
        if (lane == 0) {                                                      \
            if (w > 0) { xa##g.x = 0.f; ya##g.x = 0.f; }                      \
            if (w > 1) { xa##g.y = 0.f; ya##g.y = 0.f; }                      \
            if (w > 2) { xa##g.z = 0.f; ya##g.z = 0.f; }                      \
        }                                                                     \
        acc0.x += xa##g.x + ya##g.x; acc0.y += xa##g.y + ya##g.y;             \
        acc0.z += xa##g.z + ya##g.z; acc0.w += xa##g.w + ya##g.w;             \
        acc1.x += xb##g.x + yb##g.x; acc1.y += xb##g.y + yb##g.y;             \
        acc1.z += xb##g.z + yb##g.z; acc1.w += xb##g.w + yb##g.w;             \
        acc2.x += xc##g.x; acc2.y += xc##g.y;                                 \
        acc2.z += xc##g.z; acc2.w += xc##g.w;                                 \
        acc3.x += xd##g.x; acc3.y += xd##g.y;                                 \
        acc3.z += xd##g.z; acc3.w += xd##g.w;                                 \
    }

    LOADP(0, fT0, fB0, nvT0, nvB0)
    LOADP(1, fT1, fB1, nvT1, nvB1)
    LOADP(2, fT2, fB2, nvT2, nvB2)
    CONSP(0, nvT0, nvB0)
    LOADP(3, fT3, fB3, nvT3, nvB3)
    CONSP(1, nvT1, nvB1)
    CONSP(2, nvT2, nvB2)
    CONSP(3, nvT3, nvB3)
#undef LOADP
#undef CONSP

    // dump: lds[w][4*(lane+64*g)+comp] — bijective onto [0,1024) per wave
    float4* lrow = (float4*)lds[w];
    lrow[lane]       = acc0;
    lrow[lane + 64]  = acc1;
    lrow[lane + 128] = acc2;
    lrow[lane + 192] = acc3;
    if (tid < 32) lds[tid >> 3][1024 + (tid & 7)] = 0.f;
    __syncthreads();

    // partial[b][t][d] = sum over waves of lds[wv][d + wv]; float4 store
    float* outp = partial + ((size_t)b * CHUNKS + t) * NN;
    {
        const int d0 = tid * 4;
        float4 o;
        o.x = (lds[0][d0]     + lds[1][d0 + 1]) + (lds[2][d0 + 2] + lds[3][d0 + 3]);
        o.y = (lds[0][d0 + 1] + lds[1][d0 + 2]) + (lds[2][d0 + 3] + lds[3][d0 + 4]);
        o.z = (lds[0][d0 + 2] + lds[1][d0 + 3]) + (lds[2][d0 + 4] + lds[3][d0 + 5]);
        o.w = (lds[0][d0 + 3] + lds[1][d0 + 4]) + (lds[2][d0 + 5] + lds[3][d0 + 6]);
        ((float4*)outp)[tid] = o;
    }
}

// ---------------------------------------------------------------------------
// Kernel 2: reduce chunk partials -> parity-split means, v2 (4x parallelism).
// 512 blocks x 256 thr: block (b, dq of 64 d); thread (d, c-quarter) sums 8
// chunks independently; 4->1 combine via LDS.
__global__ __launch_bounds__(256) void reduce_waves(const float* __restrict__ partial,
                                                    float* __restrict__ wpm) {
    __shared__ float slo_s[256], shi_s[256];
    const int blk = blockIdx.x;
    const int b = blk >> 3;
    const int dq = blk & 7;
    const int tid = threadIdx.x;
    const int d = dq * 64 + (tid & 63);
    const int cq = tid >> 6;            // 0..3
    const float* pb = partial + (size_t)b * CHUNKS * NN;
    float slo = 0.f, shi = 0.f;
#pragma unroll
    for (int j = 0; j < 8; ++j) {
        const int c = cq * 8 + j;
        slo += pb[c * NN + d];
        shi += pb[c * NN + d + 512];
    }
    slo_s[tid] = slo; shi_s[tid] = shi;
    __syncthreads();
    if (tid < 64) {
        const float l = (slo_s[tid] + slo_s[tid + 64]) + (slo_s[tid + 128] + slo_s[tid + 192]);
        const float h = (shi_s[tid] + shi_s[tid + 64]) + (shi_s[tid + 128] + shi_s[tid + 192]);
        const float wlo = l / (float)(NN - d);
        const float whi = h / (float)(512 - d);
        wpm[(size_t)b * NN + d]       = wlo + whi;   // wp
        wpm[(size_t)b * NN + 512 + d] = wlo - whi;   // wm
    }
}

// ---------------------------------------------------------------------------
// Kernel 3: even/odd-decimated DFT, float2 twiddles, fast-trig table build.
__global__ __launch_bounds__(512) void dft_part(const float* __restrict__ wpm,
                                                float* __restrict__ kparts) {
    __shared__ float wp[512], wm[512];
    __shared__ float2 tw[NN];       // (cos, -sin)
    __shared__ float redmax[8], redsum[8];
    const int ks = blockIdx.x & (KS - 1);
    const int b = blockIdx.x >> 3;
    const int tid = threadIdx.x;
    const float C = 6.283185307179586f / 1024.0f;

    {
        const float* src = wpm + (size_t)b * NN;
        wp[tid & 511] = src[tid & 511];
        wm[tid & 511] = src[512 + (tid & 511)];
        float s0, c0, s1, c1;
        __sincosf((float)tid * C, &s0, &c0);
        __sincosf((float)(tid + 512) * C, &s1, &c1);
        tw[tid]       = make_float2(c0, -s0);
        tw[tid + 512] = make_float2(c1, -s1);
    }
    __syncthreads();

    const int k = 1 + ks * 64 + (tid >> 3);
    const int dp = tid & 7;
    const float* wsel = (k & 1) ? wm : wp;
    const int kstep = (k << 3) & (NN - 1);

    float re = 0.f, im = 0.f;
    int t = (k * dp) & (NN - 1);
#pragma unroll 8
    for (int it = 0; it < 64; ++it) {
        const float2 c = tw[t];
        const float wv = wsel[dp + 8 * it];
        re = fmaf(wv, c.x, re);
        im = fmaf(wv, c.y, im);
        t = (t + kstep) & (NN - 1);
    }
    re += __shfl_xor(re, 1, 64); re += __shfl_xor(re, 2, 64); re += __shfl_xor(re, 4, 64);
    im += __shfl_xor(im, 1, 64); im += __shfl_xor(im, 2, 64); im += __shfl_xor(im, 4, 64);
    const float spec = sqrtf(re * re + im * im);

    float mx = spec;
    float sm = (dp == 0) ? spec : 0.f;
    for (int off = 8; off < 64; off <<= 1) {
        mx = fmaxf(mx, __shfl_xor(mx, off, 64));
        sm += __shfl_xor(sm, off, 64);
    }
    const int wid = tid >> 6, lane = tid & 63;
    if (lane == 0) { redmax[wid] = mx; redsum[wid] = sm; }
    __syncthreads();
    if (tid == 0) {
        float M = redmax[0], S = redsum[0];
        for (int i = 1; i < 8; ++i) { M = fmaxf(M, redmax[i]); S += redsum[i]; }
        kparts[((size_t)b * KS + ks) * 2 + 0] = M;
        kparts[((size_t)b * KS + ks) * 2 + 1] = S;
    }
}

// ---------------------------------------------------------------------------
// Kernel 4: judgement per batch, mean over batches.
__global__ __launch_bounds__(64) void finalize(const float* __restrict__ kparts,
                                               float* __restrict__ out) {
    const int lane = threadIdx.x;
    float M = 0.f, S = 0.f;
#pragma unroll
    for (int s = 0; s < KS; ++s) {
        M = fmaxf(M, kparts[((size_t)lane * KS + s) * 2 + 0]);
        S += kparts[((size_t)lane * KS + s) * 2 + 1];
    }
    float j = 1.0f - M / S;
    for (int off = 32; off; off >>= 1) j += __shfl_xor(j, off, 64);
    if (lane == 0) out[0] = j * (1.0f / 64.0f);
}

// ---------------------------------------------------------------------------
extern "C" void kernel_launch(void* const* d_in, const int* in_sizes, int n_in,
                              void* d_out, int out_size, void* d_ws, size_t ws_size,
                              hipStream_t stream) {
    const float* attns = (const float*)d_in[0];
    float* out = (float*)d_out;

    float* partial = (float*)d_ws;
    float* wpm     = partial + (size_t)BB * CHUNKS * NN;
    float* kparts  = wpm + (size_t)BB * NN;

    diag_partial<<<dim3(CHUNKS, BB), 256, 0, stream>>>(attns, partial);
    reduce_waves<<<BB * 8, 256, 0, stream>>>(partial, wpm);
    dft_part<<<BB * KS, 512, 0, stream>>>(wpm, kparts);
    finalize<<<1, 64, 0, stream>>>(kparts, out);
}